// Round 7
// baseline (174.177 us; speedup 1.0000x reference)
//
#include <hip/hip_runtime.h>

#define BB 4096
#define TT 10
#define SS 301
#define HH 5
#define OO 3

typedef _Float16 h2 __attribute__((ext_vector_type(2)));

#if defined(__has_builtin)
#if __has_builtin(__builtin_amdgcn_fdot2)
#define HAVE_FDOT2 1
#endif
#endif

__device__ __forceinline__ h2 pkrtz(float a, float b){
    return __builtin_bit_cast(h2, __builtin_amdgcn_cvt_pkrtz(a, b));
}
__device__ __forceinline__ h2 sp2h(float c){ h2 r; r.x = (_Float16)c; r.y = (_Float16)c; return r; }
__device__ __forceinline__ h2 fma2h(h2 a, h2 b, h2 c){ return __builtin_elementwise_fma(a, b, c); }

// rcp of both halves (d in [33, 900]): f32 magic seed (validated r4-r6) + 2 packed fp16 Newton.
__device__ __forceinline__ h2 rcp_pair(h2 d){
    float dx = (float)d.x, dy = (float)d.y;
    float sx = __uint_as_float(0x7EF311C3u - __float_as_uint(dx));
    float sy = __uint_as_float(0x7EF311C3u - __float_as_uint(dy));
    h2 y = pkrtz(sx, sy);
    h2 nd = -d;
    const h2 two = sp2h(2.0f);
    y = y * fma2h(nd, y, two);
    y = y * fma2h(nd, y, two);
    return y;
}

// Shared Pade[7/6] denominator, coeffs /4096 to fit fp16 (de in [33, 874]).
__device__ __forceinline__ h2 pade_den(h2 s){
    return fma2h(fma2h(fma2h(sp2h(0.0068359f), s, sp2h(0.769043f)), s, sp2h(15.2271f)), s, sp2h(32.9919f));
}
__device__ __forceinline__ h2 clamp48(h2 t){
    return __builtin_elementwise_min(__builtin_elementwise_max(t, sp2h(-4.8f)), sp2h(4.8f));
}

// tanh of two f32 args via packed fp16 Pade[7/6] (coeffs /4096; math validated r4-r6).
__device__ __forceinline__ void tanh_pair(float cx, float cy, float& ox, float& oy){
    h2 t = clamp48(pkrtz(cx, cy));
    h2 s = t * t;
    h2 nu = fma2h(fma2h(fma2h(sp2h(2.44141e-4f), s, sp2h(0.0922852f)), s, sp2h(4.22974f)), s, sp2h(32.9919f));
    h2 r = (nu * t) * rcp_pair(pade_den(s));
    ox = (float)r.x; oy = (float)r.y;
}
// sigmoid of two HALF-args u=a/2 (weights pre-halved): sigma = (nu*t)*rcp(de) + 0.5
__device__ __forceinline__ void sigmoid_pair(float ux, float uy, float& ox, float& oy){
    h2 t = clamp48(pkrtz(ux, uy));
    h2 s = t * t;
    h2 nu = fma2h(fma2h(fma2h(sp2h(1.22070e-4f), s, sp2h(0.0461426f)), s, sp2h(2.114868f)), s, sp2h(16.49597f));
    h2 sg = fma2h(nu * t, rcp_pair(pade_den(s)), sp2h(0.5f));
    ox = (float)sg.x; oy = (float)sg.y;
}

__global__ __launch_bounds__(256) void gru_kernel(
    const float* __restrict__ x,
    const float* __restrict__ w_ih,
    const float* __restrict__ w_hh,
    const float* __restrict__ b_ih,
    const float* __restrict__ b_hh,
    const float* __restrict__ fc_w,
    const float* __restrict__ fc_b,
    float* __restrict__ out)
{
    const int n = blockIdx.x * blockDim.x + threadIdx.x;
    const int b = n / SS;
    const int s = n - b * SS;
    if (b >= BB) return;

    // Wave-uniform weights. r,z pre-halved (sigma takes a/2). fp16 packs for dot2:
    // r/z gates: (w_x, w_h0) | (w_h1, w_h2) | (w_h3, w_h4); n gate: h0 handled scalar.
    float br_[HH], bz_[HH], bi_[HH], bh_[HH];
    float wn_[HH], whn0[HH];
#ifdef HAVE_FDOT2
    h2 wr0[HH], wr1[HH], wr2[HH], wz0[HH], wz1[HH], wz2[HH], wn1[HH], wn2[HH];
#else
    float wr_[HH], wz_[HH];
    float whr[HH][HH], whz[HH][HH], whnk[HH][HH];
#endif

    #pragma unroll
    for (int j = 0; j < HH; ++j) {
        br_[j] = 0.5f * (b_ih[j]      + b_hh[j]);
        bz_[j] = 0.5f * (b_ih[HH + j] + b_hh[HH + j]);
        bi_[j] = b_ih[2 * HH + j];
        bh_[j] = b_hh[2 * HH + j];
        wn_[j]  = w_ih[2 * HH + j];
        whn0[j] = w_hh[(2 * HH + j) * HH + 0];
#ifdef HAVE_FDOT2
        wr0[j] = pkrtz(0.5f * w_ih[j],                0.5f * w_hh[j * HH + 0]);
        wr1[j] = pkrtz(0.5f * w_hh[j * HH + 1],       0.5f * w_hh[j * HH + 2]);
        wr2[j] = pkrtz(0.5f * w_hh[j * HH + 3],       0.5f * w_hh[j * HH + 4]);
        wz0[j] = pkrtz(0.5f * w_ih[HH + j],           0.5f * w_hh[(HH + j) * HH + 0]);
        wz1[j] = pkrtz(0.5f * w_hh[(HH + j) * HH + 1], 0.5f * w_hh[(HH + j) * HH + 2]);
        wz2[j] = pkrtz(0.5f * w_hh[(HH + j) * HH + 3], 0.5f * w_hh[(HH + j) * HH + 4]);
        wn1[j] = pkrtz(w_hh[(2 * HH + j) * HH + 1],    w_hh[(2 * HH + j) * HH + 2]);
        wn2[j] = pkrtz(w_hh[(2 * HH + j) * HH + 3],    w_hh[(2 * HH + j) * HH + 4]);
#else
        wr_[j] = 0.5f * w_ih[j];
        wz_[j] = 0.5f * w_ih[HH + j];
        #pragma unroll
        for (int k = 0; k < HH; ++k) {
            whr[j][k]  = 0.5f * w_hh[j * HH + k];
            whz[j][k]  = 0.5f * w_hh[(HH + j) * HH + k];
            whnk[j][k] = w_hh[(2 * HH + j) * HH + k];
        }
#endif
    }

    // Preload the 10 inputs (coalesced across the wave per t).
    float xt[TT];
    const float* xp = x + (size_t)b * (TT * SS) + s;
    #pragma unroll
    for (int t = 0; t < TT; ++t) xt[t] = xp[t * SS];

    float h[HH];
    #pragma unroll
    for (int j = 0; j < HH; ++j) h[j] = 0.0f;

    #pragma unroll
    for (int t = 0; t < TT; ++t) {
        const float xv = xt[t];
        float ur[HH], uz[HH], ah[HH], ai[HH];

#ifdef HAVE_FDOT2
        // fp16 packs of (x, h) for this step; fp32-accumulating dot2 matvec.
        h2 px = pkrtz(xv,   h[0]);
        h2 p1 = pkrtz(h[1], h[2]);
        h2 p2 = pkrtz(h[3], h[4]);
        #pragma unroll
        for (int j = 0; j < HH; ++j) {
            ur[j] = __builtin_amdgcn_fdot2(px, wr0[j],
                      __builtin_amdgcn_fdot2(p1, wr1[j],
                        __builtin_amdgcn_fdot2(p2, wr2[j], br_[j], false), false), false);
            uz[j] = __builtin_amdgcn_fdot2(px, wz0[j],
                      __builtin_amdgcn_fdot2(p1, wz1[j],
                        __builtin_amdgcn_fdot2(p2, wz2[j], bz_[j], false), false), false);
            ah[j] = __fmaf_rn(whn0[j], h[0],
                      __builtin_amdgcn_fdot2(p1, wn1[j],
                        __builtin_amdgcn_fdot2(p2, wn2[j], bh_[j], false), false));
            ai[j] = __fmaf_rn(xv, wn_[j], bi_[j]);
        }
#else
        #pragma unroll
        for (int j = 0; j < HH; ++j) {
            float a = __fmaf_rn(xv, wr_[j], br_[j]);
            float c = __fmaf_rn(xv, wz_[j], bz_[j]);
            float d = bh_[j];
            #pragma unroll
            for (int k = 0; k < HH; ++k) {
                a = __fmaf_rn(whr[j][k],  h[k], a);
                c = __fmaf_rn(whz[j][k],  h[k], c);
                d = __fmaf_rn(whnk[j][k], h[k], d);
            }
            ur[j] = a; uz[j] = c; ah[j] = d;
            ai[j] = __fmaf_rn(xv, wn_[j], bi_[j]);
        }
#endif

        // sigma on (r,z) pairs per channel
        float r[HH], z[HH];
        #pragma unroll
        for (int j = 0; j < HH; ++j) sigmoid_pair(ur[j], uz[j], r[j], z[j]);

        // tanh over channel pairs
        float cc[HH], nv[HH];
        #pragma unroll
        for (int j = 0; j < HH; ++j) cc[j] = __fmaf_rn(r[j], ah[j], ai[j]);
        float dummy;
        tanh_pair(cc[0], cc[1], nv[0], nv[1]);
        tanh_pair(cc[2], cc[3], nv[2], nv[3]);
        tanh_pair(cc[4], cc[4], nv[4], dummy);

        // h' = z*(h - n) + n
        #pragma unroll
        for (int j = 0; j < HH; ++j) h[j] = __fmaf_rn(z[j], h[j] - nv[j], nv[j]);
    }

    // y = fc(h); out[(b*O + o)*S + s]
    float* op = out + (size_t)b * (OO * SS) + s;
    #pragma unroll
    for (int o = 0; o < OO; ++o) {
        float y = fc_b[o];
        #pragma unroll
        for (int k = 0; k < HH; ++k) y = __fmaf_rn(fc_w[o * HH + k], h[k], y);
        op[o * SS] = y;
    }
}

extern "C" void kernel_launch(void* const* d_in, const int* in_sizes, int n_in,
                              void* d_out, int out_size, void* d_ws, size_t ws_size,
                              hipStream_t stream) {
    const float* x    = (const float*)d_in[0];
    const float* w_ih = (const float*)d_in[1];
    const float* w_hh = (const float*)d_in[2];
    const float* b_ih = (const float*)d_in[3];
    const float* b_hh = (const float*)d_in[4];
    const float* fc_w = (const float*)d_in[5];
    const float* fc_b = (const float*)d_in[6];
    float* out = (float*)d_out;

    const int N = BB * SS;                 // 1,232,896
    const int block = 256;
    const int grid = (N + block - 1) / block;  // 4816 exactly
    gru_kernel<<<grid, block, 0, stream>>>(x, w_ih, w_hh, b_ih, b_hh, fc_w, fc_b, out);
}